// Round 7
// baseline (463.208 us; speedup 1.0000x reference)
//
#include <hip/hip_runtime.h>

// Problem constants
#define HEADS 8
#define CH    64
#define HC    512   // HEADS*CH
#define NGR   64
#define NEGS  0.2f
#define BNB   60    // bn_stats blocks
#define WPTOT (512*32 + 512*64 + 512*64)   // Wt prep elements = 81920
#define WPB   ((WPTOT + 255) / 256)        // 320 blocks

typedef __attribute__((ext_vector_type(8))) short short8;
typedef __attribute__((ext_vector_type(4))) float f32x4;

__device__ __forceinline__ float lrelu(float v) {
    return (v > 0.f) ? v : NEGS * v;
}

// bf16 (as ushort) -> fp32
__device__ __forceinline__ float bf2f_lo(unsigned u) { return __uint_as_float(u << 16); }
__device__ __forceinline__ float bf2f_hi(unsigned u) { return __uint_as_float(u & 0xffff0000u); }
__device__ __forceinline__ float bf2f_us(unsigned short u) {
    return __uint_as_float(((unsigned)u) << 16);
}

// fp32 -> bf16 bits, round-to-nearest-even (finite inputs)
__device__ __forceinline__ unsigned bf16bits(float f) {
    unsigned u = __float_as_uint(f);
    return (u + 0x7fffu + ((u >> 16) & 1u)) >> 16;
}
__device__ __forceinline__ unsigned packbf2(float a, float b) {
    return bf16bits(a) | (bf16bits(b) << 16);
}

// ---------------------------------------------------------------------------
// D1: blocks [0,BNB) = BN stats partials; [BNB,+gE2) = CSR count;
// [+WPB) = W -> Wt bf16 transpose prep; [+5) = u/v precompute (depends only
// on W/a inputs, so it runs here instead of serializing in D2).
__global__ void stats_count_kernel(const float* __restrict__ x, float* __restrict__ partials,
                                   int N, int chunk,
                                   const int* __restrict__ ei, int E, int E2,
                                   int* __restrict__ counts,
                                   const float* __restrict__ W1, const float* __restrict__ W2,
                                   const float* __restrict__ W3,
                                   ushort* __restrict__ wt1, ushort* __restrict__ wt2,
                                   ushort* __restrict__ wt3,
                                   const float* __restrict__ a1s, const float* __restrict__ a1d,
                                   const float* __restrict__ a2s, const float* __restrict__ a2d,
                                   const float* __restrict__ a3s, const float* __restrict__ a3d,
                                   float* __restrict__ uv) {
    int t = threadIdx.x;
    if (blockIdx.x >= BNB) {
        int bi = blockIdx.x - BNB;
        int gE2b = (E2 + 255) >> 8;
        if (bi < gE2b) {
            int i = bi * blockDim.x + t;
            if (i < E2) {
                int dst = (i < E) ? ei[E + i] : (i - E);
                atomicAdd(counts + dst, 1);
            }
            return;
        }
        bi -= gE2b;
        if (bi < WPB) {
            // Wt prep: wt[c][k] = bf16(W[k][c]); layer 1 padded to K=32 w/ 0.
            int i = bi * 256 + t;
            if (i < 512 * 32) {
                int c = i >> 5, k = i & 31;
                wt1[i] = (k < 16) ? (ushort)bf16bits(W1[k * HC + c]) : (ushort)0;
            } else if (i < 512 * 32 + 512 * 64) {
                int j = i - 512 * 32;
                int c = j >> 6, k = j & 63;
                wt2[j] = (ushort)bf16bits(W2[k * HC + c]);
            } else if (i < WPTOT) {
                int j = i - (512 * 32 + 512 * 64);
                int c = j >> 6, k = j & 63;
                wt3[j] = (ushort)bf16bits(W3[k * HC + c]);
            }
            return;
        }
        bi -= WPB;   // 0..4: uv roles
        // uv layout: [0]=u1(16x8) [128]=v1 [256]=u2(64x8) [768]=v2
        //            [1280]=u3 [1792]=v3
        const float *W, *as, *ad;
        int K, uofs, kbase;
        if (bi == 0)      { W = W1; as = a1s; ad = a1d; K = 16; uofs = 0;    kbase = 0;
                            if (t >= 128) return; }
        else if (bi <= 2) { W = W2; as = a2s; ad = a2d; K = 64; uofs = 256;  kbase = (bi - 1) * 32; }
        else              { W = W3; as = a3s; ad = a3d; K = 64; uofs = 1280; kbase = (bi - 3) * 32; }
        int k = kbase + (t >> 3), h = t & 7;
        const float* wr = W + (size_t)k * HC + h * CH;
        const float* sr = as + h * CH;
        const float* dr = ad + h * CH;
        float su = 0.f, sv = 0.f;
#pragma unroll 8
        for (int c = 0; c < CH; c++) { su += wr[c] * sr[c]; sv += wr[c] * dr[c]; }
        uv[uofs + k * 8 + h] = su;
        uv[uofs + K * 8 + k * 8 + h] = sv;
        return;
    }
    int n0 = blockIdx.x * chunk;
    int n1 = min(n0 + chunk, N);
    float s[16], q[16];
#pragma unroll
    for (int i = 0; i < 16; i++) { s[i] = 0.f; q[i] = 0.f; }
    for (int r = n0 + t; r < n1; r += 256) {
        const float4* xr = (const float4*)(x + (size_t)r * 16);
#pragma unroll
        for (int i = 0; i < 4; i++) {
            float4 v = xr[i];
            s[4*i+0] += v.x; q[4*i+0] += v.x * v.x;
            s[4*i+1] += v.y; q[4*i+1] += v.y * v.y;
            s[4*i+2] += v.z; q[4*i+2] += v.z * v.z;
            s[4*i+3] += v.w; q[4*i+3] += v.w * v.w;
        }
    }
#pragma unroll
    for (int k = 0; k < 16; k++) {
#pragma unroll
        for (int off = 32; off; off >>= 1) {
            s[k] += __shfl_down(s[k], off);
            q[k] += __shfl_down(q[k], off);
        }
    }
    __shared__ float lds[4][32];
    int lane = t & 63, wid = t >> 6;
    if (lane == 0) {
#pragma unroll
        for (int k = 0; k < 16; k++) { lds[wid][k] = s[k]; lds[wid][16 + k] = q[k]; }
    }
    __syncthreads();
    if (t < 32) {
        float v = lds[0][t] + lds[1][t] + lds[2][t] + lds[3][t];
        partials[(size_t)blockIdx.x * 32 + t] = v;
    }
}

// ---------------------------------------------------------------------------
// D2: block 0 = BN finalize; block 1 = CSR scan. (uv moved to D1.)
__global__ void finalize_scan_kernel(const float* __restrict__ partials,
                                     float* __restrict__ stats,
                                     const float* __restrict__ gamma,
                                     const float* __restrict__ beta,
                                     int N, int nblk,
                                     const int* __restrict__ counts,
                                     int* __restrict__ rowptr,
                                     int* __restrict__ cursor) {
    int t = threadIdx.x;
    if (blockIdx.x == 0) {
        // BN finalize: stats[32..47]=scale, stats[48..63]=shift.
        __shared__ float sums[32];
        if (t < 32) {
            float v = 0.f;
            for (int b = 0; b < nblk; b++) v += partials[(size_t)b * 32 + t];
            sums[t] = v;
        }
        __syncthreads();
        if (t < 16) {
            float invn = 1.f / (float)N;
            float mean = sums[t] * invn;
            float var  = sums[16 + t] * invn - mean * mean;
            float sc   = gamma[t] * rsqrtf(var + 1e-5f);
            stats[32 + t] = sc;
            stats[48 + t] = beta[t] - mean * sc;
        }
        return;
    }
    // Single-block scan, 8 elems/thread (2x int4), 1024 threads.
    __shared__ int wsum[16];
    __shared__ int base_s;
    int lane = t & 63, wid = t >> 6;
    if (t == 0) base_s = 0;
    __syncthreads();
    for (int start = 0; start < N; start += 8192) {
        int i0 = start + t * 8;
        int e[8];
#pragma unroll
        for (int i = 0; i < 8; i++) e[i] = 0;
        if (i0 + 7 < N) {
            int4 a = *(const int4*)(counts + i0);
            int4 b = *(const int4*)(counts + i0 + 4);
            e[0] = a.x; e[1] = a.y; e[2] = a.z; e[3] = a.w;
            e[4] = b.x; e[5] = b.y; e[6] = b.z; e[7] = b.w;
        } else {
#pragma unroll
            for (int i = 0; i < 8; i++)
                if (i0 + i < N) e[i] = counts[i0 + i];
        }
        int tot = 0;
#pragma unroll
        for (int i = 0; i < 8; i++) tot += e[i];
        int v = tot;
#pragma unroll
        for (int off = 1; off < 64; off <<= 1) {
            int u = __shfl_up(v, off);
            if (lane >= off) v += u;
        }
        if (lane == 63) wsum[wid] = v;
        __syncthreads();
        if (t < 16) {
            int w = wsum[t];
#pragma unroll
            for (int off = 1; off < 16; off <<= 1) {
                int u = __shfl_up(w, off);
                if (t >= off) w += u;
            }
            wsum[t] = w;
        }
        __syncthreads();
        int run = base_s + (v - tot) + (wid ? wsum[wid - 1] : 0);
        int p[8];
#pragma unroll
        for (int i = 0; i < 8; i++) { p[i] = run; run += e[i]; }
        if (i0 + 7 < N) {
            *(int4*)(rowptr + i0)     = make_int4(p[0], p[1], p[2], p[3]);
            *(int4*)(rowptr + i0 + 4) = make_int4(p[4], p[5], p[6], p[7]);
            *(int4*)(cursor + i0)     = make_int4(p[0], p[1], p[2], p[3]);
            *(int4*)(cursor + i0 + 4) = make_int4(p[4], p[5], p[6], p[7]);
        } else {
#pragma unroll
            for (int i = 0; i < 8; i++)
                if (i0 + i < N) { rowptr[i0 + i] = p[i]; cursor[i0 + i] = p[i]; }
        }
        __syncthreads();
        if (t == 0) base_s += wsum[15];
        __syncthreads();
    }
    if (t == 0) rowptr[N] = base_s;
}

// ---------------------------------------------------------------------------
// GEMM v10 (MFMA): h[N,512](bf16) = xin[N,Kin] @ W[Kin,512], via 16x16x32
// bf16 matrix cores. Block = 64 rows x 256 cols, 4 waves; wave w -> 64-col
// quadrant x all 64 rows (acc[4][4], 16 ds_read_b128/wave).
// __launch_bounds__(256,4): LDS 40KB (KT=64) x 4 = 160KB/CU fits exactly ->
// 4 blocks/CU, so the full 940-block grid is co-resident in ONE round
// (at 3/CU = 768 slots, 172 straggler blocks ran a ~idle second round).
// SCAT=true (layer 1): blocks past `gemmBlocks` run the CSR scatter.
// A/B tiles in XOR-swizzled LDS (byte ^= (row&7)<<4 -> 2-way = free). Wt is
// pre-transposed [512][KT] bf16 so A and B fragments are contiguous-K
// ds_read_b128 (K-permutation cancels between A and B). D layout (m89):
// col=lane&15 (channel), row=(lane>>4)*4+j (node).
// Layer 1: Kin=16 zero-padded to KT=32; BN scale/shift fused into staging.
// asv/adv epilogue on col-block 0, reading the staged bf16 x-tile.
template <int KT, bool SCAT>
__launch_bounds__(256, 4)
__global__ void gemm_kernel(const float* __restrict__ xin, const ushort* __restrict__ wt,
                            ushort* __restrict__ hout, int N, int Kin,
                            const float* __restrict__ scale, const float* __restrict__ shift,
                            const float* __restrict__ u, const float* __restrict__ v,
                            float* __restrict__ asv, float* __restrict__ adv,
                            const int* __restrict__ ei, int E, int E2,
                            int* __restrict__ cursor, int* __restrict__ src_csr,
                            int gemmBlocks) {
    if (SCAT && (int)blockIdx.x >= gemmBlocks) {
        int i = ((int)blockIdx.x - gemmBlocks) * 256 + threadIdx.x;
        if (i < E2) {
            int src, dst;
            if (i < E) { src = ei[i]; dst = ei[E + i]; }
            else       { src = i - E; dst = src; }
            int pos = atomicAdd(cursor + dst, 1);
            src_csr[pos] = src;
        }
        return;
    }
    __shared__ uint4 xs4[(64 * 2 * KT) / 16];
    __shared__ uint4 ws4[(256 * 2 * KT) / 16];
    char* xsb = (char*)xs4;
    char* wsb = (char*)ws4;
    const int t = threadIdx.x;
    const int row0 = (blockIdx.x >> 1) * 64;
    const int cb0 = (blockIdx.x & 1) * 256;

    // ---- stage x tile -> bf16 LDS (swizzled), zero-pad rows>=N and k>=Kin
    const int F4R = KT / 4;
    for (int idx = t; idx < 64 * F4R; idx += 256) {
        int row = idx / F4R;
        int c4 = (idx - row * F4R) * 4;
        int node = row0 + row;
        float4 vv = make_float4(0.f, 0.f, 0.f, 0.f);
        if (node < N && c4 < Kin) {
            vv = *(const float4*)(xin + (size_t)node * Kin + c4);
            if (scale) {
                vv.x = vv.x * scale[c4 + 0] + shift[c4 + 0];
                vv.y = vv.y * scale[c4 + 1] + shift[c4 + 1];
                vv.z = vv.z * scale[c4 + 2] + shift[c4 + 2];
                vv.w = vv.w * scale[c4 + 3] + shift[c4 + 3];
            }
        }
        uint2 pk = make_uint2(packbf2(vv.x, vv.y), packbf2(vv.z, vv.w));
        int off = (row * (2 * KT) + c4 * 2) ^ ((row & 7) << 4);
        *(uint2*)(xsb + off) = pk;
    }
    // ---- stage Wt slice (rows cb0..cb0+255) -> LDS (swizzled)
    const int U16R = (2 * KT) / 16;
    for (int uu = t; uu < 256 * U16R; uu += 256) {
        int row = uu / U16R;
        int uir = uu - row * U16R;
        uint4 wv = *(const uint4*)((const char*)wt + (size_t)(cb0 + row) * (2 * KT) + uir * 16);
        int off = (row * (2 * KT) + uir * 16) ^ ((row & 7) << 4);
        *(uint4*)(wsb + off) = wv;
    }
    __syncthreads();

    const int lane = t & 63;
    const int w = t >> 6;              // wave -> 64-col quadrant
    const int l15 = lane & 15;
    const int kg = lane >> 4;          // k-group 0..3
    const f32x4 zero = {0.f, 0.f, 0.f, 0.f};
    f32x4 acc[4][4];                   // [row-frag][col-frag]
#pragma unroll
    for (int i = 0; i < 4; i++)
#pragma unroll
        for (int jj = 0; jj < 4; jj++) acc[i][jj] = zero;
#pragma unroll
    for (int ks = 0; ks < KT / 32; ks++) {
        int ko2 = (ks * 32 + kg * 8) * 2;
        short8 av[4], bv[4];
#pragma unroll
        for (int rf = 0; rf < 4; rf++) {
            int arow = rf * 16 + l15;
            int aoff = (arow * (2 * KT) + ko2) ^ ((arow & 7) << 4);
            av[rf] = *(const short8*)(xsb + aoff);
        }
#pragma unroll
        for (int cf = 0; cf < 4; cf++) {
            int brow = w * 64 + cf * 16 + l15;
            int boff = (brow * (2 * KT) + ko2) ^ ((brow & 7) << 4);
            bv[cf] = *(const short8*)(wsb + boff);
        }
#pragma unroll
        for (int rf = 0; rf < 4; rf++)
#pragma unroll
            for (int cf = 0; cf < 4; cf++)
                acc[rf][cf] = __builtin_amdgcn_mfma_f32_16x16x32_bf16(av[rf], bv[cf],
                                                                      acc[rf][cf], 0, 0, 0);
    }
    // ---- store D -> hout (bf16)
#pragma unroll
    for (int rf = 0; rf < 4; rf++) {
#pragma unroll
        for (int cf = 0; cf < 4; cf++) {
            int chan = cb0 + w * 64 + cf * 16 + l15;
#pragma unroll
            for (int j = 0; j < 4; j++) {
                int node = row0 + rf * 16 + kg * 4 + j;
                if (node < N)
                    hout[(size_t)node * HC + chan] = (ushort)bf16bits(acc[rf][cf][j]);
            }
        }
    }
    // ---- asv/adv epilogue (only on col-block 0 to avoid duplicate writes)
    if (cb0 == 0) {
        int h = t & 7;
        for (int rr = t >> 3; rr < 64; rr += 32) {
            int node = row0 + rr;
            if (node >= N) continue;
            float su = 0.f, sv = 0.f;
            for (int kb = 0; kb < Kin / 8; kb++) {
                int off = (rr * (2 * KT) + kb * 16) ^ ((rr & 7) << 4);
                short8 xv = *(const short8*)(xsb + off);
#pragma unroll
                for (int j = 0; j < 8; j++) {
                    float f = bf2f_us((unsigned short)xv[j]);
                    su += f * u[(kb * 8 + j) * 8 + h];
                    sv += f * v[(kb * 8 + j) * 8 + h];
                }
            }
            asv[(size_t)node * 8 + h] = su;
            adv[(size_t)node * 8 + h] = sv;
        }
    }
}

// ---------------------------------------------------------------------------
// Fused softmax+aggregation: one WAVE per dst node, 4-edge unroll (VGPR 32,
// occ ~68%). PROVEN WALL: 74-75 us, FETCH 247 MB = 8 XCDs x full hbuf
// (compulsory for a random graph), rate 3.34 TB/s = binding fabric limit.
// Head-split (r2): FETCH -60% but 8x VALU dup -> 114 us. FP8 messages (r4):
// absmax 2.4e-5 > 5.7e-6 threshold -> dead. bf16 + this shape is the optimum.
__global__ void agg_kernel(const int* __restrict__ rp, const int* __restrict__ src_csr,
                           const float* __restrict__ asv, const float* __restrict__ adv,
                           const ushort* __restrict__ hbuf, const float* __restrict__ bias,
                           float* __restrict__ xout, int N, int dorelu) {
    int gw = (blockIdx.x * blockDim.x + threadIdx.x) >> 6;  // node id
    int lane = threadIdx.x & 63;
    if (gw >= N) return;
    int head = lane >> 3;
    size_t lofs = 8 * (size_t)lane;
    int jb = rp[gw], je = rp[gw + 1];
    float ad = adv[(size_t)gw * 8 + head];
    float acc[8];
#pragma unroll
    for (int r = 0; r < 8; r++) acc[r] = 0.f;
    float den = 0.f;
    int j = jb;
    for (; j + 4 <= je; j += 4) {
        int s0 = src_csr[j],     s1 = src_csr[j + 1];
        int s2 = src_csr[j + 2], s3 = src_csr[j + 3];
        float w0 = __expf(lrelu(asv[(size_t)s0 * 8 + head] + ad));
        float w1 = __expf(lrelu(asv[(size_t)s1 * 8 + head] + ad));
        float w2 = __expf(lrelu(asv[(size_t)s2 * 8 + head] + ad));
        float w3 = __expf(lrelu(asv[(size_t)s3 * 8 + head] + ad));
        uint4 p0 = *(const uint4*)(hbuf + (size_t)s0 * HC + lofs);
        uint4 p1 = *(const uint4*)(hbuf + (size_t)s1 * HC + lofs);
        uint4 p2 = *(const uint4*)(hbuf + (size_t)s2 * HC + lofs);
        uint4 p3 = *(const uint4*)(hbuf + (size_t)s3 * HC + lofs);
        den += (w0 + w1) + (w2 + w3);
        acc[0] += w0 * bf2f_lo(p0.x); acc[1] += w0 * bf2f_hi(p0.x);
        acc[2] += w0 * bf2f_lo(p0.y); acc[3] += w0 * bf2f_hi(p0.y);
        acc[4] += w0 * bf2f_lo(p0.z); acc[5] += w0 * bf2f_hi(p0.z);
        acc[6] += w0 * bf2f_lo(p0.w); acc[7] += w0 * bf2f_hi(p0.w);
        acc[0] += w1 * bf2f_lo(p1.x); acc[1] += w1 * bf2f_hi(p1.x);
        acc[2] += w1 * bf2f_lo(p1.y); acc[3] += w1 * bf2f_hi(p1.y);
        acc[4] += w1 * bf2f_lo(p1.z); acc[5] += w1 * bf2f_hi(p1.z);
        acc[6] += w1 * bf2f_lo(p1.w); acc[7] += w1 * bf2f_hi(p1.w);
        acc[0] += w2 * bf2f_lo(p2.x); acc[1] += w2 * bf2f_hi(p2.x);
        acc[2] += w2 * bf2f_lo(p2.y); acc[3] += w2 * bf2f_hi(p2.y);
        acc[4] += w2 * bf2f_lo(p2.z); acc[5] += w2 * bf2f_hi(p2.z);
        acc[6] += w2 * bf2f_lo(p2.w); acc[7] += w2 * bf2f_hi(p2.w);
        acc[0] += w3 * bf2f_lo(p3.x); acc[1] += w3 * bf2f_hi(p3.x);
        acc[2] += w3 * bf2f_lo(p3.y); acc[3] += w3 * bf2f_hi(p3.y);
        acc[4] += w3 * bf2f_lo(p3.z); acc[5] += w3 * bf2f_hi(p3.z);
        acc[6] += w3 * bf2f_lo(p3.w); acc[7] += w3 * bf2f_hi(p3.w);
    }
    for (; j < je; j++) {
        int s0 = src_csr[j];
        float w0 = __expf(lrelu(asv[(size_t)s0 * 8 + head] + ad));
        uint4 p0 = *(const uint4*)(hbuf + (size_t)s0 * HC + lofs);
        den += w0;
        acc[0] += w0 * bf2f_lo(p0.x); acc[1] += w0 * bf2f_hi(p0.x);
        acc[2] += w0 * bf2f_lo(p0.y); acc[3] += w0 * bf2f_hi(p0.y);
        acc[4] += w0 * bf2f_lo(p0.z); acc[5] += w0 * bf2f_hi(p0.z);
        acc[6] += w0 * bf2f_lo(p0.w); acc[7] += w0 * bf2f_hi(p0.w);
    }
    float inv = 1.f / (den + 1e-16f);
#pragma unroll
    for (int r = 0; r < 8; r++) {
        acc[r] *= inv;
        acc[r] += __shfl_xor(acc[r], 8);
        acc[r] += __shfl_xor(acc[r], 16);
        acc[r] += __shfl_xor(acc[r], 32);
    }
    if (lane < 8) {
        const float4* b4 = (const float4*)(bias + 8 * lane);
        float4 bv0 = b4[0], bv1 = b4[1];
        float4 o0, o1;
        o0.x = acc[0] * 0.125f + bv0.x;
        o0.y = acc[1] * 0.125f + bv0.y;
        o0.z = acc[2] * 0.125f + bv0.z;
        o0.w = acc[3] * 0.125f + bv0.w;
        o1.x = acc[4] * 0.125f + bv1.x;
        o1.y = acc[5] * 0.125f + bv1.y;
        o1.z = acc[6] * 0.125f + bv1.z;
        o1.w = acc[7] * 0.125f + bv1.w;
        if (dorelu) {
            o0.x = fmaxf(o0.x, 0.f); o0.y = fmaxf(o0.y, 0.f);
            o0.z = fmaxf(o0.z, 0.f); o0.w = fmaxf(o0.w, 0.f);
            o1.x = fmaxf(o1.x, 0.f); o1.y = fmaxf(o1.y, 0.f);
            o1.z = fmaxf(o1.z, 0.f); o1.w = fmaxf(o1.w, 0.f);
        }
        float4* op = (float4*)(xout + (size_t)gw * CH + 8 * lane);
        op[0] = o0;
        op[1] = o1;
    }
}

// ---------------------------------------------------------------------------
// Fused mean-pool + linear: one block per graph (batch sorted, binary search).
__global__ void poolfinal_kernel(const float* __restrict__ x, const int* __restrict__ batch,
                                 const float* __restrict__ linW, const float* __restrict__ linb,
                                 float* __restrict__ out, int N) {
    int g = blockIdx.x;
    int lo = 0, hi = N;
    while (lo < hi) { int m = (lo + hi) >> 1; if (batch[m] < g) lo = m + 1; else hi = m; }
    int lo2 = lo, hi2 = N;
    while (lo2 < hi2) { int m = (lo2 + hi2) >> 1; if (batch[m] < g + 1) lo2 = m + 1; else hi2 = m; }
    int n0 = lo, n1 = lo2;
    int c  = threadIdx.x & 63;
    int nl = threadIdx.x >> 6;
    float acc = 0.f;
    for (int n = n0 + nl; n < n1; n += 4)
        acc += x[(size_t)n * CH + c];
    __shared__ float lds[4][64];
    lds[nl][c] = acc;
    __syncthreads();
    __shared__ float pooled[64];
    if (threadIdx.x < 64) {
        float cnt = (float)max(n1 - n0, 1);
        pooled[threadIdx.x] = (lds[0][threadIdx.x] + lds[1][threadIdx.x] +
                               lds[2][threadIdx.x] + lds[3][threadIdx.x]) / cnt;
    }
    __syncthreads();
    if (threadIdx.x < 2) {
        int k = threadIdx.x;
        float s = 0.f;
#pragma unroll
        for (int cc = 0; cc < CH; cc++) s += pooled[cc] * linW[cc * 2 + k];
        out[g * 2 + k] = s + linb[k];
    }
}

// ---------------------------------------------------------------------------
extern "C" void kernel_launch(void* const* d_in, const int* in_sizes, int n_in,
                              void* d_out, int out_size, void* d_ws, size_t ws_size,
                              hipStream_t stream) {
    const float* x      = (const float*)d_in[0];
    const int*   ei     = (const int*)d_in[1];
    const int*   batch  = (const int*)d_in[3];
    const float* gamma  = (const float*)d_in[4];
    const float* beta   = (const float*)d_in[5];
    const float* W1     = (const float*)d_in[6];
    const float* a1s    = (const float*)d_in[7];
    const float* a1d    = (const float*)d_in[8];
    const float* b1     = (const float*)d_in[9];
    const float* W2     = (const float*)d_in[10];
    const float* a2s    = (const float*)d_in[11];
    const float* a2d    = (const float*)d_in[12];
    const float* b2     = (const float*)d_in[13];
    const float* W3     = (const float*)d_in[14];
    const float* a3s    = (const float*)d_in[15];
    const float* a3d    = (const float*)d_in[16];
    const float* b3     = (const float*)d_in[17];
    const float* linW   = (const float*)d_in[18];
    const float* linb   = (const float*)d_in[19];
    float* out = (float*)d_out;

    const int N  = in_sizes[0] / 16;
    const int E  = in_sizes[1] / 2;
    const int E2 = E + N;

    // Workspace layout (256B aligned slices)
    char* p = (char*)d_ws;
    size_t off = 0;
    auto alloc = [&](size_t bytes) {
        void* r = p + off;
        off += (bytes + 255) & ~(size_t)255;
        return r;
    };
    ushort* hbuf     = (ushort*)alloc((size_t)N * HC * 2);   // bf16 h
    float* xa        = (float*)alloc((size_t)N * CH * 4);
    float* xb        = (float*)alloc((size_t)N * CH * 4);
    float* asv       = (float*)alloc((size_t)N * HEADS * 4);
    float* adv       = (float*)alloc((size_t)N * HEADS * 4);
    float* stats     = (float*)alloc(64 * 4);
    float* partials  = (float*)alloc((size_t)BNB * 32 * 4);
    float* uv        = (float*)alloc(2304 * 4);
    int*   rowptr    = (int*)alloc((size_t)(N + 1) * 4);
    int*   cursor    = (int*)alloc((size_t)N * 4);
    int*   counts    = (int*)alloc((size_t)N * 4);
    int*   src_csr   = (int*)alloc((size_t)E2 * 4);
    ushort* wt1      = (ushort*)alloc(512 * 32 * 2);  // Wt bf16, layer1 K-pad 32
    ushort* wt2      = (ushort*)alloc(512 * 64 * 2);
    ushort* wt3      = (ushort*)alloc(512 * 64 * 2);
    (void)ws_size;

    const int TB = 256;
    int gE2 = (E2 + TB - 1) / TB;
    int gWv = (N * 64 + TB - 1) / TB;      // one wave per node
    int bnChunk = (N + BNB - 1) / BNB;
    int gb = ((N + 63) / 64) * 2;          // MFMA gemm: 64-row x 256-col tiles (1D)

    // zero-init count accumulators
    hipMemsetAsync(counts, 0, (size_t)N * 4, stream);

    // D1: BN stats || CSR count || Wt prep || u/v precompute (merged)
    stats_count_kernel<<<BNB + gE2 + WPB + 5, TB, 0, stream>>>(
        x, partials, N, bnChunk, ei, E, E2, counts,
        W1, W2, W3, wt1, wt2, wt3,
        a1s, a1d, a2s, a2d, a3s, a3d, uv);
    // D2: BN finalize + CSR scan
    finalize_scan_kernel<<<2, 1024, 0, stream>>>(partials, stats, gamma, beta, N, BNB,
                                                 counts, rowptr, cursor);

    // ---- Layer 1 GEMM || CSR scatter (independent, merged dispatch) ----
    gemm_kernel<32, true><<<gb + gE2, TB, 0, stream>>>(x, wt1, hbuf, N, 16,
                                                       stats + 32, stats + 48,
                                                       uv + 0, uv + 128, asv, adv,
                                                       ei, E, E2, cursor, src_csr, gb);
    agg_kernel<<<gWv, TB, 0, stream>>>(rowptr, src_csr, asv, adv, hbuf, b1, xa, N, 1);

    // ---- Layer 2 ----
    gemm_kernel<64, false><<<gb, TB, 0, stream>>>(xa, wt2, hbuf, N, 64, nullptr, nullptr,
                                                  uv + 256, uv + 768, asv, adv,
                                                  nullptr, 0, 0, nullptr, nullptr, gb);
    agg_kernel<<<gWv, TB, 0, stream>>>(rowptr, src_csr, asv, adv, hbuf, b2, xb, N, 1);

    // ---- Layer 3 ----
    gemm_kernel<64, false><<<gb, TB, 0, stream>>>(xb, wt3, hbuf, N, 64, nullptr, nullptr,
                                                  uv + 1280, uv + 1792, asv, adv,
                                                  nullptr, 0, 0, nullptr, nullptr, gb);
    agg_kernel<<<gWv, TB, 0, stream>>>(rowptr, src_csr, asv, adv, hbuf, b3, xa, N, 0);

    // ---- Fused mean-pool + linear ----
    poolfinal_kernel<<<NGR, TB, 0, stream>>>(xa, batch, linW, linb, out, N);
}

// Round 8
// 449.959 us; speedup vs baseline: 1.0294x; 1.0294x over previous
//
#include <hip/hip_runtime.h>

// Problem constants
#define HEADS 8
#define CH    64
#define HC    512   // HEADS*CH
#define NGR   64
#define NEGS  0.2f
#define BNB   60    // bn_stats blocks
#define WPTOT (512*32 + 512*64 + 512*64)   // Wt prep elements = 81920
#define WPB   ((WPTOT + 255) / 256)        // 320 blocks

typedef __attribute__((ext_vector_type(8))) short short8;
typedef __attribute__((ext_vector_type(4))) float f32x4;

__device__ __forceinline__ float lrelu(float v) {
    return (v > 0.f) ? v : NEGS * v;
}

// bf16 (as ushort) -> fp32
__device__ __forceinline__ float bf2f_lo(unsigned u) { return __uint_as_float(u << 16); }
__device__ __forceinline__ float bf2f_hi(unsigned u) { return __uint_as_float(u & 0xffff0000u); }
__device__ __forceinline__ float bf2f_us(unsigned short u) {
    return __uint_as_float(((unsigned)u) << 16);
}

// fp32 -> bf16 bits, round-to-nearest-even (finite inputs)
__device__ __forceinline__ unsigned bf16bits(float f) {
    unsigned u = __float_as_uint(f);
    return (u + 0x7fffu + ((u >> 16) & 1u)) >> 16;
}
__device__ __forceinline__ unsigned packbf2(float a, float b) {
    return bf16bits(a) | (bf16bits(b) << 16);
}

// ---------------------------------------------------------------------------
// D1: blocks [0,BNB) = BN stats partials; [BNB,BNB+gE2) = CSR count;
// [BNB+gE2,..) = W -> Wt bf16 transpose prep (independent, merged dispatch).
__global__ void stats_count_kernel(const float* __restrict__ x, float* __restrict__ partials,
                                   int N, int chunk,
                                   const int* __restrict__ ei, int E, int E2,
                                   int* __restrict__ counts,
                                   const float* __restrict__ W1, const float* __restrict__ W2,
                                   const float* __restrict__ W3,
                                   ushort* __restrict__ wt1, ushort* __restrict__ wt2,
                                   ushort* __restrict__ wt3) {
    if (blockIdx.x >= BNB) {
        int bi = blockIdx.x - BNB;
        int gE2 = (E2 + 255) >> 8;
        if (bi < gE2) {
            int i = bi * blockDim.x + threadIdx.x;
            if (i < E2) {
                int dst = (i < E) ? ei[E + i] : (i - E);
                atomicAdd(counts + dst, 1);
            }
            return;
        }
        // Wt prep: wt[c][k] = bf16(W[k][c]); layer 1 padded to K=32 with zeros.
        int i = (bi - gE2) * 256 + threadIdx.x;
        if (i < 512 * 32) {
            int c = i >> 5, k = i & 31;
            wt1[i] = (k < 16) ? (ushort)bf16bits(W1[k * HC + c]) : (ushort)0;
        } else if (i < 512 * 32 + 512 * 64) {
            int j = i - 512 * 32;
            int c = j >> 6, k = j & 63;
            wt2[j] = (ushort)bf16bits(W2[k * HC + c]);
        } else if (i < WPTOT) {
            int j = i - (512 * 32 + 512 * 64);
            int c = j >> 6, k = j & 63;
            wt3[j] = (ushort)bf16bits(W3[k * HC + c]);
        }
        return;
    }
    int n0 = blockIdx.x * chunk;
    int n1 = min(n0 + chunk, N);
    float s[16], q[16];
#pragma unroll
    for (int i = 0; i < 16; i++) { s[i] = 0.f; q[i] = 0.f; }
    for (int r = n0 + threadIdx.x; r < n1; r += 256) {
        const float4* xr = (const float4*)(x + (size_t)r * 16);
#pragma unroll
        for (int i = 0; i < 4; i++) {
            float4 v = xr[i];
            s[4*i+0] += v.x; q[4*i+0] += v.x * v.x;
            s[4*i+1] += v.y; q[4*i+1] += v.y * v.y;
            s[4*i+2] += v.z; q[4*i+2] += v.z * v.z;
            s[4*i+3] += v.w; q[4*i+3] += v.w * v.w;
        }
    }
#pragma unroll
    for (int k = 0; k < 16; k++) {
#pragma unroll
        for (int off = 32; off; off >>= 1) {
            s[k] += __shfl_down(s[k], off);
            q[k] += __shfl_down(q[k], off);
        }
    }
    __shared__ float lds[4][32];
    int lane = threadIdx.x & 63, wid = threadIdx.x >> 6;
    if (lane == 0) {
#pragma unroll
        for (int k = 0; k < 16; k++) { lds[wid][k] = s[k]; lds[wid][16 + k] = q[k]; }
    }
    __syncthreads();
    int t = threadIdx.x;
    if (t < 32) {
        float v = lds[0][t] + lds[1][t] + lds[2][t] + lds[3][t];
        partials[(size_t)blockIdx.x * 32 + t] = v;
    }
}

// ---------------------------------------------------------------------------
// D2: blocks 0-2 = u/v precompute; block 3 = BN finalize; block 4 = CSR scan.
// uv layout: [0]=u1(16x8) [128]=v1 [256]=u2(64x8) [768]=v2 [1280]=u3 [1792]=v3
__global__ void uv_scan_kernel(const float* __restrict__ W1, const float* __restrict__ a1s,
                               const float* __restrict__ a1d,
                               const float* __restrict__ W2, const float* __restrict__ a2s,
                               const float* __restrict__ a2d,
                               const float* __restrict__ W3, const float* __restrict__ a3s,
                               const float* __restrict__ a3d,
                               float* __restrict__ uv,
                               const float* __restrict__ partials, float* __restrict__ stats,
                               const float* __restrict__ gamma, const float* __restrict__ beta,
                               int N, int nblk,
                               const int* __restrict__ counts, int* __restrict__ rowptr,
                               int* __restrict__ cursor) {
    int role = blockIdx.x;
    int t = threadIdx.x;
    if (role == 3) {
        __shared__ float sums[32];
        if (t < 32) {
            float v = 0.f;
            for (int b = 0; b < nblk; b++) v += partials[(size_t)b * 32 + t];
            sums[t] = v;
        }
        __syncthreads();
        if (t < 16) {
            float invn = 1.f / (float)N;
            float mean = sums[t] * invn;
            float var  = sums[16 + t] * invn - mean * mean;
            float sc   = gamma[t] * rsqrtf(var + 1e-5f);
            stats[32 + t] = sc;
            stats[48 + t] = beta[t] - mean * sc;
        }
        return;
    }
    if (role == 4) {
        __shared__ int wsum[16];
        __shared__ int base_s;
        int lane = t & 63, wid = t >> 6;
        if (t == 0) base_s = 0;
        __syncthreads();
        for (int start = 0; start < N; start += 8192) {
            int i0 = start + t * 8;
            int e[8];
#pragma unroll
            for (int i = 0; i < 8; i++) e[i] = 0;
            if (i0 + 7 < N) {
                int4 a = *(const int4*)(counts + i0);
                int4 b = *(const int4*)(counts + i0 + 4);
                e[0] = a.x; e[1] = a.y; e[2] = a.z; e[3] = a.w;
                e[4] = b.x; e[5] = b.y; e[6] = b.z; e[7] = b.w;
            } else {
#pragma unroll
                for (int i = 0; i < 8; i++)
                    if (i0 + i < N) e[i] = counts[i0 + i];
            }
            int tot = 0;
#pragma unroll
            for (int i = 0; i < 8; i++) tot += e[i];
            int v = tot;
#pragma unroll
            for (int off = 1; off < 64; off <<= 1) {
                int u = __shfl_up(v, off);
                if (lane >= off) v += u;
            }
            if (lane == 63) wsum[wid] = v;
            __syncthreads();
            if (t < 16) {
                int w = wsum[t];
#pragma unroll
                for (int off = 1; off < 16; off <<= 1) {
                    int u = __shfl_up(w, off);
                    if (t >= off) w += u;
                }
                wsum[t] = w;
            }
            __syncthreads();
            int run = base_s + (v - tot) + (wid ? wsum[wid - 1] : 0);
            int p[8];
#pragma unroll
            for (int i = 0; i < 8; i++) { p[i] = run; run += e[i]; }
            if (i0 + 7 < N) {
                *(int4*)(rowptr + i0)     = make_int4(p[0], p[1], p[2], p[3]);
                *(int4*)(rowptr + i0 + 4) = make_int4(p[4], p[5], p[6], p[7]);
                *(int4*)(cursor + i0)     = make_int4(p[0], p[1], p[2], p[3]);
                *(int4*)(cursor + i0 + 4) = make_int4(p[4], p[5], p[6], p[7]);
            } else {
#pragma unroll
                for (int i = 0; i < 8; i++)
                    if (i0 + i < N) { rowptr[i0 + i] = p[i]; cursor[i0 + i] = p[i]; }
            }
            __syncthreads();
            if (t == 0) base_s += wsum[15];
            __syncthreads();
        }
        if (t == 0) rowptr[N] = base_s;
        return;
    }
    // roles 0-2: uv for layer `role`
    const float* W  = (role == 0) ? W1  : (role == 1) ? W2  : W3;
    const float* as = (role == 0) ? a1s : (role == 1) ? a2s : a3s;
    const float* ad = (role == 0) ? a1d : (role == 1) ? a2d : a3d;
    int K = (role == 0) ? 16 : 64;
    int uofs = (role == 0) ? 0 : (role == 1) ? 256 : 1280;
    if (t >= K * 8) return;
    int k = t >> 3, h = t & 7;
    const float* wr = W + (size_t)k * HC + h * CH;
    const float* sr = as + h * CH;
    const float* dr = ad + h * CH;
    float su = 0.f, sv = 0.f;
#pragma unroll 8
    for (int c = 0; c < CH; c++) { su += wr[c] * sr[c]; sv += wr[c] * dr[c]; }
    uv[uofs + k * 8 + h] = su;
    uv[uofs + K * 8 + k * 8 + h] = sv;
}

// ---------------------------------------------------------------------------
// GEMM v11 (MFMA): h[N,512](bf16) = xin[N,Kin] @ W[Kin,512], via 16x16x32
// bf16 matrix cores. Base = round-5 best (v8, (256,3), merged scatter);
// single change: for KT=64 the 32KB Wt tile is staged via
// __builtin_amdgcn_global_load_lds width=16 (async direct-to-LDS, no VGPR
// round-trip / no per-thread load-wait before ds_write). Swizzle handled as
// linear-LDS-dest + pre-swizzled global source: for 128B rows the
// (row&7)<<4 XOR is row-local => involution => src = dst ^ mask.
// (KT=32 keeps the VGPR path: its swizzle crosses 64B rows, not an
// involution; layer-1 tile is only 16KB.)
// SCAT=true (layer 1): blocks past `gemmBlocks` run the CSR scatter.
// D layout (m89): col=lane&15 (channel), row=(lane>>4)*4+j (node).
// Layer 1: Kin=16 zero-padded to KT=32; BN scale/shift fused into staging.
// asv/adv epilogue on col-block 0, reading the staged bf16 x-tile.
template <int KT, bool SCAT>
__launch_bounds__(256, 3)
__global__ void gemm_kernel(const float* __restrict__ xin, const ushort* __restrict__ wt,
                            ushort* __restrict__ hout, int N, int Kin,
                            const float* __restrict__ scale, const float* __restrict__ shift,
                            const float* __restrict__ u, const float* __restrict__ v,
                            float* __restrict__ asv, float* __restrict__ adv,
                            const int* __restrict__ ei, int E, int E2,
                            int* __restrict__ cursor, int* __restrict__ src_csr,
                            int gemmBlocks) {
    if (SCAT && (int)blockIdx.x >= gemmBlocks) {
        int i = ((int)blockIdx.x - gemmBlocks) * 256 + threadIdx.x;
        if (i < E2) {
            int src, dst;
            if (i < E) { src = ei[i]; dst = ei[E + i]; }
            else       { src = i - E; dst = src; }
            int pos = atomicAdd(cursor + dst, 1);
            src_csr[pos] = src;
        }
        return;
    }
    __shared__ uint4 xs4[(64 * 2 * KT) / 16];
    __shared__ uint4 ws4[(256 * 2 * KT) / 16];
    char* xsb = (char*)xs4;
    char* wsb = (char*)ws4;
    const int t = threadIdx.x;
    const int row0 = (blockIdx.x >> 1) * 64;
    const int cb0 = (blockIdx.x & 1) * 256;

    // ---- stage Wt slice (rows cb0..cb0+255) -> LDS (swizzled)
    if constexpr (KT == 64) {
        // Async direct-to-LDS. Lane l of wave w writes linear LDS bytes
        // [base + l*16, +16) with base = (it*256 + w*64)*16; the global
        // source for linear dest X is X ^ ((row&7)<<4) (involution).
        const char* wslice = (const char*)wt + (size_t)cb0 * (2 * KT);
#pragma unroll
        for (int it = 0; it < 8; it++) {
            int X = (it * 256 + t) * 16;
            int srcb = X ^ (((X >> 7) & 7) << 4);
            __builtin_amdgcn_global_load_lds(
                (const __attribute__((address_space(1))) void*)(wslice + srcb),
                (__attribute__((address_space(3))) void*)(wsb + (it * 256 + (t & ~63)) * 16),
                16, 0, 0);
        }
    } else {
        const int U16R = (2 * KT) / 16;
        for (int uu = t; uu < 256 * U16R; uu += 256) {
            int row = uu / U16R;
            int uir = uu - row * U16R;
            uint4 wv = *(const uint4*)((const char*)wt + (size_t)(cb0 + row) * (2 * KT) + uir * 16);
            int off = (row * (2 * KT) + uir * 16) ^ ((row & 7) << 4);
            *(uint4*)(wsb + off) = wv;
        }
    }
    // ---- stage x tile -> bf16 LDS (swizzled), zero-pad rows>=N and k>=Kin
    // (VGPR path: needs f32->bf16 cvt; overlaps the in-flight async Wt loads)
    const int F4R = KT / 4;
    for (int idx = t; idx < 64 * F4R; idx += 256) {
        int row = idx / F4R;
        int c4 = (idx - row * F4R) * 4;
        int node = row0 + row;
        float4 vv = make_float4(0.f, 0.f, 0.f, 0.f);
        if (node < N && c4 < Kin) {
            vv = *(const float4*)(xin + (size_t)node * Kin + c4);
            if (scale) {
                vv.x = vv.x * scale[c4 + 0] + shift[c4 + 0];
                vv.y = vv.y * scale[c4 + 1] + shift[c4 + 1];
                vv.z = vv.z * scale[c4 + 2] + shift[c4 + 2];
                vv.w = vv.w * scale[c4 + 3] + shift[c4 + 3];
            }
        }
        uint2 pk = make_uint2(packbf2(vv.x, vv.y), packbf2(vv.z, vv.w));
        int off = (row * (2 * KT) + c4 * 2) ^ ((row & 7) << 4);
        *(uint2*)(xsb + off) = pk;
    }
    __syncthreads();

    const int lane = t & 63;
    const int w = t >> 6;              // wave -> 64-col quadrant
    const int l15 = lane & 15;
    const int kg = lane >> 4;          // k-group 0..3
    const f32x4 zero = {0.f, 0.f, 0.f, 0.f};
    f32x4 acc[4][4];                   // [row-frag][col-frag]
#pragma unroll
    for (int i = 0; i < 4; i++)
#pragma unroll
        for (int jj = 0; jj < 4; jj++) acc[i][jj] = zero;
#pragma unroll
    for (int ks = 0; ks < KT / 32; ks++) {
        int ko2 = (ks * 32 + kg * 8) * 2;
        short8 av[4], bv[4];
#pragma unroll
        for (int rf = 0; rf < 4; rf++) {
            int arow = rf * 16 + l15;
            int aoff = (arow * (2 * KT) + ko2) ^ ((arow & 7) << 4);
            av[rf] = *(const short8*)(xsb + aoff);
        }
#pragma unroll
        for (int cf = 0; cf < 4; cf++) {
            int brow = w * 64 + cf * 16 + l15;
            int boff = (brow * (2 * KT) + ko2) ^ ((brow & 7) << 4);
            bv[cf] = *(const short8*)(wsb + boff);
        }
#pragma unroll
        for (int rf = 0; rf < 4; rf++)
#pragma unroll
            for (int cf = 0; cf < 4; cf++)
                acc[rf][cf] = __builtin_amdgcn_mfma_f32_16x16x32_bf16(av[rf], bv[cf],
                                                                      acc[rf][cf], 0, 0, 0);
    }
    // ---- store D -> hout (bf16)
#pragma unroll
    for (int rf = 0; rf < 4; rf++) {
#pragma unroll
        for (int cf = 0; cf < 4; cf++) {
            int chan = cb0 + w * 64 + cf * 16 + l15;
#pragma unroll
            for (int j = 0; j < 4; j++) {
                int node = row0 + rf * 16 + kg * 4 + j;
                if (node < N)
                    hout[(size_t)node * HC + chan] = (ushort)bf16bits(acc[rf][cf][j]);
            }
        }
    }
    // ---- asv/adv epilogue (only on col-block 0 to avoid duplicate writes)
    if (cb0 == 0) {
        int h = t & 7;
        for (int rr = t >> 3; rr < 64; rr += 32) {
            int node = row0 + rr;
            if (node >= N) continue;
            float su = 0.f, sv = 0.f;
            for (int kb = 0; kb < Kin / 8; kb++) {
                int off = (rr * (2 * KT) + kb * 16) ^ ((rr & 7) << 4);
                short8 xv = *(const short8*)(xsb + off);
#pragma unroll
                for (int j = 0; j < 8; j++) {
                    float f = bf2f_us((unsigned short)xv[j]);
                    su += f * u[(kb * 8 + j) * 8 + h];
                    sv += f * v[(kb * 8 + j) * 8 + h];
                }
            }
            asv[(size_t)node * 8 + h] = su;
            adv[(size_t)node * 8 + h] = sv;
        }
    }
}

// ---------------------------------------------------------------------------
// Fused softmax+aggregation: one WAVE per dst node, 4-edge unroll (VGPR 32,
// occ ~68%). PROVEN WALL: 74-75 us, FETCH 247 MB = 8 XCDs x full hbuf
// (compulsory for a random graph), rate 3.34 TB/s = binding fabric limit.
// Head-split (r2): FETCH -60% but 8x VALU dup -> 114 us. FP8 messages (r4):
// absmax 2.4e-5 > 5.7e-6 threshold -> dead. bf16 + this shape is the optimum.
__global__ void agg_kernel(const int* __restrict__ rp, const int* __restrict__ src_csr,
                           const float* __restrict__ asv, const float* __restrict__ adv,
                           const ushort* __restrict__ hbuf, const float* __restrict__ bias,
                           float* __restrict__ xout, int N, int dorelu) {
    int gw = (blockIdx.x * blockDim.x + threadIdx.x) >> 6;  // node id
    int lane = threadIdx.x & 63;
    if (gw >= N) return;
    int head = lane >> 3;
    size_t lofs = 8 * (size_t)lane;
    int jb = rp[gw], je = rp[gw + 1];
    float ad = adv[(size_t)gw * 8 + head];
    float acc[8];
#pragma unroll
    for (int r = 0; r < 8; r++) acc[r] = 0.f;
    float den = 0.f;
    int j = jb;
    for (; j + 4 <= je; j += 4) {
        int s0 = src_csr[j],     s1 = src_csr[j + 1];
        int s2 = src_csr[j + 2], s3 = src_csr[j + 3];
        float w0 = __expf(lrelu(asv[(size_t)s0 * 8 + head] + ad));
        float w1 = __expf(lrelu(asv[(size_t)s1 * 8 + head] + ad));
        float w2 = __expf(lrelu(asv[(size_t)s2 * 8 + head] + ad));
        float w3 = __expf(lrelu(asv[(size_t)s3 * 8 + head] + ad));
        uint4 p0 = *(const uint4*)(hbuf + (size_t)s0 * HC + lofs);
        uint4 p1 = *(const uint4*)(hbuf + (size_t)s1 * HC + lofs);
        uint4 p2 = *(const uint4*)(hbuf + (size_t)s2 * HC + lofs);
        uint4 p3 = *(const uint4*)(hbuf + (size_t)s3 * HC + lofs);
        den += (w0 + w1) + (w2 + w3);
        acc[0] += w0 * bf2f_lo(p0.x); acc[1] += w0 * bf2f_hi(p0.x);
        acc[2] += w0 * bf2f_lo(p0.y); acc[3] += w0 * bf2f_hi(p0.y);
        acc[4] += w0 * bf2f_lo(p0.z); acc[5] += w0 * bf2f_hi(p0.z);
        acc[6] += w0 * bf2f_lo(p0.w); acc[7] += w0 * bf2f_hi(p0.w);
        acc[0] += w1 * bf2f_lo(p1.x); acc[1] += w1 * bf2f_hi(p1.x);
        acc[2] += w1 * bf2f_lo(p1.y); acc[3] += w1 * bf2f_hi(p1.y);
        acc[4] += w1 * bf2f_lo(p1.z); acc[5] += w1 * bf2f_hi(p1.z);
        acc[6] += w1 * bf2f_lo(p1.w); acc[7] += w1 * bf2f_hi(p1.w);
        acc[0] += w2 * bf2f_lo(p2.x); acc[1] += w2 * bf2f_hi(p2.x);
        acc[2] += w2 * bf2f_lo(p2.y); acc[3] += w2 * bf2f_hi(p2.y);
        acc[4] += w2 * bf2f_lo(p2.z); acc[5] += w2 * bf2f_hi(p2.z);
        acc[6] += w2 * bf2f_lo(p2.w); acc[7] += w2 * bf2f_hi(p2.w);
        acc[0] += w3 * bf2f_lo(p3.x); acc[1] += w3 * bf2f_hi(p3.x);
        acc[2] += w3 * bf2f_lo(p3.y); acc[3] += w3 * bf2f_hi(p3.y);
        acc[4] += w3 * bf2f_lo(p3.z); acc[5] += w3 * bf2f_hi(p3.z);
        acc[6] += w3 * bf2f_lo(p3.w); acc[7] += w3 * bf2f_hi(p3.w);
    }
    for (; j < je; j++) {
        int s0 = src_csr[j];
        float w0 = __expf(lrelu(asv[(size_t)s0 * 8 + head] + ad));
        uint4 p0 = *(const uint4*)(hbuf + (size_t)s0 * HC + lofs);
        den += w0;
        acc[0] += w0 * bf2f_lo(p0.x); acc[1] += w0 * bf2f_hi(p0.x);
        acc[2] += w0 * bf2f_lo(p0.y); acc[3] += w0 * bf2f_hi(p0.y);
        acc[4] += w0 * bf2f_lo(p0.z); acc[5] += w0 * bf2f_hi(p0.z);
        acc[6] += w0 * bf2f_lo(p0.w); acc[7] += w0 * bf2f_hi(p0.w);
    }
    float inv = 1.f / (den + 1e-16f);
#pragma unroll
    for (int r = 0; r < 8; r++) {
        acc[r] *= inv;
        acc[r] += __shfl_xor(acc[r], 8);
        acc[r] += __shfl_xor(acc[r], 16);
        acc[r] += __shfl_xor(acc[r], 32);
    }
    if (lane < 8) {
        const float4* b4 = (const float4*)(bias + 8 * lane);
        float4 bv0 = b4[0], bv1 = b4[1];
        float4 o0, o1;
        o0.x = acc[0] * 0.125f + bv0.x;
        o0.y = acc[1] * 0.125f + bv0.y;
        o0.z = acc[2] * 0.125f + bv0.z;
        o0.w = acc[3] * 0.125f + bv0.w;
        o1.x = acc[4] * 0.125f + bv1.x;
        o1.y = acc[5] * 0.125f + bv1.y;
        o1.z = acc[6] * 0.125f + bv1.z;
        o1.w = acc[7] * 0.125f + bv1.w;
        if (dorelu) {
            o0.x = fmaxf(o0.x, 0.f); o0.y = fmaxf(o0.y, 0.f);
            o0.z = fmaxf(o0.z, 0.f); o0.w = fmaxf(o0.w, 0.f);
            o1.x = fmaxf(o1.x, 0.f); o1.y = fmaxf(o1.y, 0.f);
            o1.z = fmaxf(o1.z, 0.f); o1.w = fmaxf(o1.w, 0.f);
        }
        float4* op = (float4*)(xout + (size_t)gw * CH + 8 * lane);
        op[0] = o0;
        op[1] = o1;
    }
}

// ---------------------------------------------------------------------------
// Fused mean-pool + linear: one block per graph (batch sorted, binary search).
__global__ void poolfinal_kernel(const float* __restrict__ x, const int* __restrict__ batch,
                                 const float* __restrict__ linW, const float* __restrict__ linb,
                                 float* __restrict__ out, int N) {
    int g = blockIdx.x;
    int lo = 0, hi = N;
    while (lo < hi) { int m = (lo + hi) >> 1; if (batch[m] < g) lo = m + 1; else hi = m; }
    int lo2 = lo, hi2 = N;
    while (lo2 < hi2) { int m = (lo2 + hi2) >> 1; if (batch[m] < g + 1) lo2 = m + 1; else hi2 = m; }
    int n0 = lo, n1 = lo2;
    int c  = threadIdx.x & 63;
    int nl = threadIdx.x >> 6;
    float acc = 0.f;
    for (int n = n0 + nl; n < n1; n += 4)
        acc += x[(size_t)n * CH + c];
    __shared__ float lds[4][64];
    lds[nl][c] = acc;
    __syncthreads();
    __shared__ float pooled[64];
    if (threadIdx.x < 64) {
        float cnt = (float)max(n1 - n0, 1);
        pooled[threadIdx.x] = (lds[0][threadIdx.x] + lds[1][threadIdx.x] +
                               lds[2][threadIdx.x] + lds[3][threadIdx.x]) / cnt;
    }
    __syncthreads();
    if (threadIdx.x < 2) {
        int k = threadIdx.x;
        float s = 0.f;
#pragma unroll
        for (int cc = 0; cc < CH; cc++) s += pooled[cc] * linW[cc * 2 + k];
        out[g * 2 + k] = s + linb[k];
    }
}

// ---------------------------------------------------------------------------
extern "C" void kernel_launch(void* const* d_in, const int* in_sizes, int n_in,
                              void* d_out, int out_size, void* d_ws, size_t ws_size,
                              hipStream_t stream) {
    const float* x      = (const float*)d_in[0];
    const int*   ei     = (const int*)d_in[1];
    const int*   batch  = (const int*)d_in[3];
    const float* gamma  = (const float*)d_in[4];
    const float* beta   = (const float*)d_in[5];
    const float* W1     = (const float*)d_in[6];
    const float* a1s    = (const float*)d_in[7];
    const float* a1d    = (const float*)d_in[8];
    const float* b1     = (const float*)d_in[9];
    const float* W2     = (const float*)d_in[10];
    const float* a2s    = (const float*)d_in[11];
    const float* a2d    = (const float*)d_in[12];
    const float* b2     = (const float*)d_in[13];
    const float* W3     = (const float*)d_in[14];
    const float* a3s    = (const float*)d_in[15];
    const float* a3d    = (const float*)d_in[16];
    const float* b3     = (const float*)d_in[17];
    const float* linW   = (const float*)d_in[18];
    const float* linb   = (const float*)d_in[19];
    float* out = (float*)d_out;

    const int N  = in_sizes[0] / 16;
    const int E  = in_sizes[1] / 2;
    const int E2 = E + N;

    // Workspace layout (256B aligned slices)
    char* p = (char*)d_ws;
    size_t off = 0;
    auto alloc = [&](size_t bytes) {
        void* r = p + off;
        off += (bytes + 255) & ~(size_t)255;
        return r;
    };
    ushort* hbuf     = (ushort*)alloc((size_t)N * HC * 2);   // bf16 h
    float* xa        = (float*)alloc((size_t)N * CH * 4);
    float* xb        = (float*)alloc((size_t)N * CH * 4);
    float* asv       = (float*)alloc((size_t)N * HEADS * 4);
    float* adv       = (float*)alloc((size_t)N * HEADS * 4);
    float* stats     = (float*)alloc(64 * 4);
    float* partials  = (float*)alloc((size_t)BNB * 32 * 4);
    float* uv        = (float*)alloc(2304 * 4);
    int*   rowptr    = (int*)alloc((size_t)(N + 1) * 4);
    int*   cursor    = (int*)alloc((size_t)N * 4);
    int*   counts    = (int*)alloc((size_t)N * 4);
    int*   src_csr   = (int*)alloc((size_t)E2 * 4);
    ushort* wt1      = (ushort*)alloc(512 * 32 * 2);  // Wt bf16, layer1 K-pad 32
    ushort* wt2      = (ushort*)alloc(512 * 64 * 2);
    ushort* wt3      = (ushort*)alloc(512 * 64 * 2);
    (void)ws_size;

    const int TB = 256;
    int gE2 = (E2 + TB - 1) / TB;
    int gWv = (N * 64 + TB - 1) / TB;      // one wave per node
    int bnChunk = (N + BNB - 1) / BNB;
    int gb = ((N + 63) / 64) * 2;          // MFMA gemm: 64-row x 256-col tiles (1D)

    // zero-init count accumulators
    hipMemsetAsync(counts, 0, (size_t)N * 4, stream);

    // D1: BN stats partials || CSR count || Wt bf16 prep (independent, merged)
    stats_count_kernel<<<BNB + gE2 + WPB, TB, 0, stream>>>(x, partials, N, bnChunk,
                                                           ei, E, E2, counts,
                                                           W1, W2, W3, wt1, wt2, wt3);
    // D2: uv precompute + BN finalize + CSR scan (merged dispatch)
    uv_scan_kernel<<<5, 1024, 0, stream>>>(W1, a1s, a1d, W2, a2s, a2d, W3, a3s, a3d,
                                           uv, partials, stats, gamma, beta, N, BNB,
                                           counts, rowptr, cursor);

    // ---- Layer 1 GEMM || CSR scatter (independent, merged dispatch) ----
    gemm_kernel<32, true><<<gb + gE2, TB, 0, stream>>>(x, wt1, hbuf, N, 16,
                                                       stats + 32, stats + 48,
                                                       uv + 0, uv + 128, asv, adv,
                                                       ei, E, E2, cursor, src_csr, gb);
    agg_kernel<<<gWv, TB, 0, stream>>>(rowptr, src_csr, asv, adv, hbuf, b1, xa, N, 1);

    // ---- Layer 2 ----
    gemm_kernel<64, false><<<gb, TB, 0, stream>>>(xa, wt2, hbuf, N, 64, nullptr, nullptr,
                                                  uv + 256, uv + 768, asv, adv,
                                                  nullptr, 0, 0, nullptr, nullptr, gb);
    agg_kernel<<<gWv, TB, 0, stream>>>(rowptr, src_csr, asv, adv, hbuf, b2, xb, N, 1);

    // ---- Layer 3 ----
    gemm_kernel<64, false><<<gb, TB, 0, stream>>>(xb, wt3, hbuf, N, 64, nullptr, nullptr,
                                                  uv + 1280, uv + 1792, asv, adv,
                                                  nullptr, 0, 0, nullptr, nullptr, gb);
    agg_kernel<<<gWv, TB, 0, stream>>>(rowptr, src_csr, asv, adv, hbuf, b3, xa, N, 0);

    // ---- Fused mean-pool + linear ----
    poolfinal_kernel<<<NGR, TB, 0, stream>>>(xa, batch, linW, linb, out, N);
}

// Round 9
// 448.704 us; speedup vs baseline: 1.0323x; 1.0028x over previous
//
#include <hip/hip_runtime.h>

// Problem constants
#define HEADS 8
#define CH    64
#define HC    512   // HEADS*CH
#define NGR   64
#define NEGS  0.2f
#define BNB   60    // bn_stats blocks
#define WPTOT (512*32 + 512*64 + 512*64)   // Wt prep elements = 81920
#define WPB   ((WPTOT + 255) / 256)        // 320 blocks

typedef __attribute__((ext_vector_type(8))) short short8;
typedef __attribute__((ext_vector_type(4))) float f32x4;

__device__ __forceinline__ float lrelu(float v) {
    return (v > 0.f) ? v : NEGS * v;
}

// bf16 (as ushort) -> fp32
__device__ __forceinline__ float bf2f_lo(unsigned u) { return __uint_as_float(u << 16); }
__device__ __forceinline__ float bf2f_hi(unsigned u) { return __uint_as_float(u & 0xffff0000u); }
__device__ __forceinline__ float bf2f_us(unsigned short u) {
    return __uint_as_float(((unsigned)u) << 16);
}

// fp32 -> bf16 bits, round-to-nearest-even (finite inputs)
__device__ __forceinline__ unsigned bf16bits(float f) {
    unsigned u = __float_as_uint(f);
    return (u + 0x7fffu + ((u >> 16) & 1u)) >> 16;
}
__device__ __forceinline__ unsigned packbf2(float a, float b) {
    return bf16bits(a) | (bf16bits(b) << 16);
}

// ---------------------------------------------------------------------------
// D1: blocks [0,BNB) = BN stats partials; [BNB,BNB+gE2) = CSR count;
// [BNB+gE2,..) = W -> Wt bf16 transpose prep (independent, merged dispatch).
__global__ void stats_count_kernel(const float* __restrict__ x, float* __restrict__ partials,
                                   int N, int chunk,
                                   const int* __restrict__ ei, int E, int E2,
                                   int* __restrict__ counts,
                                   const float* __restrict__ W1, const float* __restrict__ W2,
                                   const float* __restrict__ W3,
                                   ushort* __restrict__ wt1, ushort* __restrict__ wt2,
                                   ushort* __restrict__ wt3) {
    if (blockIdx.x >= BNB) {
        int bi = blockIdx.x - BNB;
        int gE2 = (E2 + 255) >> 8;
        if (bi < gE2) {
            int i = bi * blockDim.x + threadIdx.x;
            if (i < E2) {
                int dst = (i < E) ? ei[E + i] : (i - E);
                atomicAdd(counts + dst, 1);
            }
            return;
        }
        // Wt prep: wt[c][k] = bf16(W[k][c]); layer 1 padded to K=32 with zeros.
        int i = (bi - gE2) * 256 + threadIdx.x;
        if (i < 512 * 32) {
            int c = i >> 5, k = i & 31;
            wt1[i] = (k < 16) ? (ushort)bf16bits(W1[k * HC + c]) : (ushort)0;
        } else if (i < 512 * 32 + 512 * 64) {
            int j = i - 512 * 32;
            int c = j >> 6, k = j & 63;
            wt2[j] = (ushort)bf16bits(W2[k * HC + c]);
        } else if (i < WPTOT) {
            int j = i - (512 * 32 + 512 * 64);
            int c = j >> 6, k = j & 63;
            wt3[j] = (ushort)bf16bits(W3[k * HC + c]);
        }
        return;
    }
    int n0 = blockIdx.x * chunk;
    int n1 = min(n0 + chunk, N);
    float s[16], q[16];
#pragma unroll
    for (int i = 0; i < 16; i++) { s[i] = 0.f; q[i] = 0.f; }
    for (int r = n0 + threadIdx.x; r < n1; r += 256) {
        const float4* xr = (const float4*)(x + (size_t)r * 16);
#pragma unroll
        for (int i = 0; i < 4; i++) {
            float4 v = xr[i];
            s[4*i+0] += v.x; q[4*i+0] += v.x * v.x;
            s[4*i+1] += v.y; q[4*i+1] += v.y * v.y;
            s[4*i+2] += v.z; q[4*i+2] += v.z * v.z;
            s[4*i+3] += v.w; q[4*i+3] += v.w * v.w;
        }
    }
#pragma unroll
    for (int k = 0; k < 16; k++) {
#pragma unroll
        for (int off = 32; off; off >>= 1) {
            s[k] += __shfl_down(s[k], off);
            q[k] += __shfl_down(q[k], off);
        }
    }
    __shared__ float lds[4][32];
    int lane = threadIdx.x & 63, wid = threadIdx.x >> 6;
    if (lane == 0) {
#pragma unroll
        for (int k = 0; k < 16; k++) { lds[wid][k] = s[k]; lds[wid][16 + k] = q[k]; }
    }
    __syncthreads();
    int t = threadIdx.x;
    if (t < 32) {
        float v = lds[0][t] + lds[1][t] + lds[2][t] + lds[3][t];
        partials[(size_t)blockIdx.x * 32 + t] = v;
    }
}

// ---------------------------------------------------------------------------
// D2: blocks 0-2 = u/v precompute; block 3 = BN finalize; block 4 = CSR scan.
// uv layout: [0]=u1(16x8) [128]=v1 [256]=u2(64x8) [768]=v2 [1280]=u3 [1792]=v3
__global__ void uv_scan_kernel(const float* __restrict__ W1, const float* __restrict__ a1s,
                               const float* __restrict__ a1d,
                               const float* __restrict__ W2, const float* __restrict__ a2s,
                               const float* __restrict__ a2d,
                               const float* __restrict__ W3, const float* __restrict__ a3s,
                               const float* __restrict__ a3d,
                               float* __restrict__ uv,
                               const float* __restrict__ partials, float* __restrict__ stats,
                               const float* __restrict__ gamma, const float* __restrict__ beta,
                               int N, int nblk,
                               const int* __restrict__ counts, int* __restrict__ rowptr,
                               int* __restrict__ cursor) {
    int role = blockIdx.x;
    int t = threadIdx.x;
    if (role == 3) {
        __shared__ float sums[32];
        if (t < 32) {
            float v = 0.f;
            for (int b = 0; b < nblk; b++) v += partials[(size_t)b * 32 + t];
            sums[t] = v;
        }
        __syncthreads();
        if (t < 16) {
            float invn = 1.f / (float)N;
            float mean = sums[t] * invn;
            float var  = sums[16 + t] * invn - mean * mean;
            float sc   = gamma[t] * rsqrtf(var + 1e-5f);
            stats[32 + t] = sc;
            stats[48 + t] = beta[t] - mean * sc;
        }
        return;
    }
    if (role == 4) {
        __shared__ int wsum[16];
        __shared__ int base_s;
        int lane = t & 63, wid = t >> 6;
        if (t == 0) base_s = 0;
        __syncthreads();
        for (int start = 0; start < N; start += 8192) {
            int i0 = start + t * 8;
            int e[8];
#pragma unroll
            for (int i = 0; i < 8; i++) e[i] = 0;
            if (i0 + 7 < N) {
                int4 a = *(const int4*)(counts + i0);
                int4 b = *(const int4*)(counts + i0 + 4);
                e[0] = a.x; e[1] = a.y; e[2] = a.z; e[3] = a.w;
                e[4] = b.x; e[5] = b.y; e[6] = b.z; e[7] = b.w;
            } else {
#pragma unroll
                for (int i = 0; i < 8; i++)
                    if (i0 + i < N) e[i] = counts[i0 + i];
            }
            int tot = 0;
#pragma unroll
            for (int i = 0; i < 8; i++) tot += e[i];
            int v = tot;
#pragma unroll
            for (int off = 1; off < 64; off <<= 1) {
                int u = __shfl_up(v, off);
                if (lane >= off) v += u;
            }
            if (lane == 63) wsum[wid] = v;
            __syncthreads();
            if (t < 16) {
                int w = wsum[t];
#pragma unroll
                for (int off = 1; off < 16; off <<= 1) {
                    int u = __shfl_up(w, off);
                    if (t >= off) w += u;
                }
                wsum[t] = w;
            }
            __syncthreads();
            int run = base_s + (v - tot) + (wid ? wsum[wid - 1] : 0);
            int p[8];
#pragma unroll
            for (int i = 0; i < 8; i++) { p[i] = run; run += e[i]; }
            if (i0 + 7 < N) {
                *(int4*)(rowptr + i0)     = make_int4(p[0], p[1], p[2], p[3]);
                *(int4*)(rowptr + i0 + 4) = make_int4(p[4], p[5], p[6], p[7]);
                *(int4*)(cursor + i0)     = make_int4(p[0], p[1], p[2], p[3]);
                *(int4*)(cursor + i0 + 4) = make_int4(p[4], p[5], p[6], p[7]);
            } else {
#pragma unroll
                for (int i = 0; i < 8; i++)
                    if (i0 + i < N) { rowptr[i0 + i] = p[i]; cursor[i0 + i] = p[i]; }
            }
            __syncthreads();
            if (t == 0) base_s += wsum[15];
            __syncthreads();
        }
        if (t == 0) rowptr[N] = base_s;
        return;
    }
    // roles 0-2: uv for layer `role`
    const float* W  = (role == 0) ? W1  : (role == 1) ? W2  : W3;
    const float* as = (role == 0) ? a1s : (role == 1) ? a2s : a3s;
    const float* ad = (role == 0) ? a1d : (role == 1) ? a2d : a3d;
    int K = (role == 0) ? 16 : 64;
    int uofs = (role == 0) ? 0 : (role == 1) ? 256 : 1280;
    if (t >= K * 8) return;
    int k = t >> 3, h = t & 7;
    const float* wr = W + (size_t)k * HC + h * CH;
    const float* sr = as + h * CH;
    const float* dr = ad + h * CH;
    float su = 0.f, sv = 0.f;
#pragma unroll 8
    for (int c = 0; c < CH; c++) { su += wr[c] * sr[c]; sv += wr[c] * dr[c]; }
    uv[uofs + k * 8 + h] = su;
    uv[uofs + K * 8 + k * 8 + h] = sv;
}

// ---------------------------------------------------------------------------
// GEMM v11 (MFMA): h[N,512](bf16) = xin[N,Kin] @ W[Kin,512], via 16x16x32
// bf16 matrix cores. Round-8 best: KT=64 Wt tile staged via async
// global_load_lds width=16 (linear LDS dest + pre-swizzled global source;
// the (row&7)<<4 XOR is row-local for 128B rows => involution).
// SCAT=true (layer 1): blocks past `gemmBlocks` run the CSR scatter.
// D layout (m89): col=lane&15 (channel), row=(lane>>4)*4+j (node).
// Layer 1: Kin=16 zero-padded to KT=32; BN scale/shift fused into staging.
// asv/adv epilogue on col-block 0, reading the staged bf16 x-tile.
template <int KT, bool SCAT>
__launch_bounds__(256, 3)
__global__ void gemm_kernel(const float* __restrict__ xin, const ushort* __restrict__ wt,
                            ushort* __restrict__ hout, int N, int Kin,
                            const float* __restrict__ scale, const float* __restrict__ shift,
                            const float* __restrict__ u, const float* __restrict__ v,
                            float* __restrict__ asv, float* __restrict__ adv,
                            const int* __restrict__ ei, int E, int E2,
                            int* __restrict__ cursor, int* __restrict__ src_csr,
                            int gemmBlocks) {
    if (SCAT && (int)blockIdx.x >= gemmBlocks) {
        int i = ((int)blockIdx.x - gemmBlocks) * 256 + threadIdx.x;
        if (i < E2) {
            int src, dst;
            if (i < E) { src = ei[i]; dst = ei[E + i]; }
            else       { src = i - E; dst = src; }
            int pos = atomicAdd(cursor + dst, 1);
            src_csr[pos] = src;
        }
        return;
    }
    __shared__ uint4 xs4[(64 * 2 * KT) / 16];
    __shared__ uint4 ws4[(256 * 2 * KT) / 16];
    char* xsb = (char*)xs4;
    char* wsb = (char*)ws4;
    const int t = threadIdx.x;
    const int row0 = (blockIdx.x >> 1) * 64;
    const int cb0 = (blockIdx.x & 1) * 256;

    // ---- stage Wt slice (rows cb0..cb0+255) -> LDS (swizzled)
    if constexpr (KT == 64) {
        const char* wslice = (const char*)wt + (size_t)cb0 * (2 * KT);
#pragma unroll
        for (int it = 0; it < 8; it++) {
            int X = (it * 256 + t) * 16;
            int srcb = X ^ (((X >> 7) & 7) << 4);
            __builtin_amdgcn_global_load_lds(
                (const __attribute__((address_space(1))) void*)(wslice + srcb),
                (__attribute__((address_space(3))) void*)(wsb + (it * 256 + (t & ~63)) * 16),
                16, 0, 0);
        }
    } else {
        const int U16R = (2 * KT) / 16;
        for (int uu = t; uu < 256 * U16R; uu += 256) {
            int row = uu / U16R;
            int uir = uu - row * U16R;
            uint4 wv = *(const uint4*)((const char*)wt + (size_t)(cb0 + row) * (2 * KT) + uir * 16);
            int off = (row * (2 * KT) + uir * 16) ^ ((row & 7) << 4);
            *(uint4*)(wsb + off) = wv;
        }
    }
    // ---- stage x tile -> bf16 LDS (swizzled), zero-pad rows>=N and k>=Kin
    const int F4R = KT / 4;
    for (int idx = t; idx < 64 * F4R; idx += 256) {
        int row = idx / F4R;
        int c4 = (idx - row * F4R) * 4;
        int node = row0 + row;
        float4 vv = make_float4(0.f, 0.f, 0.f, 0.f);
        if (node < N && c4 < Kin) {
            vv = *(const float4*)(xin + (size_t)node * Kin + c4);
            if (scale) {
                vv.x = vv.x * scale[c4 + 0] + shift[c4 + 0];
                vv.y = vv.y * scale[c4 + 1] + shift[c4 + 1];
                vv.z = vv.z * scale[c4 + 2] + shift[c4 + 2];
                vv.w = vv.w * scale[c4 + 3] + shift[c4 + 3];
            }
        }
        uint2 pk = make_uint2(packbf2(vv.x, vv.y), packbf2(vv.z, vv.w));
        int off = (row * (2 * KT) + c4 * 2) ^ ((row & 7) << 4);
        *(uint2*)(xsb + off) = pk;
    }
    __syncthreads();

    const int lane = t & 63;
    const int w = t >> 6;              // wave -> 64-col quadrant
    const int l15 = lane & 15;
    const int kg = lane >> 4;          // k-group 0..3
    const f32x4 zero = {0.f, 0.f, 0.f, 0.f};
    f32x4 acc[4][4];                   // [row-frag][col-frag]
#pragma unroll
    for (int i = 0; i < 4; i++)
#pragma unroll
        for (int jj = 0; jj < 4; jj++) acc[i][jj] = zero;
#pragma unroll
    for (int ks = 0; ks < KT / 32; ks++) {
        int ko2 = (ks * 32 + kg * 8) * 2;
        short8 av[4], bv[4];
#pragma unroll
        for (int rf = 0; rf < 4; rf++) {
            int arow = rf * 16 + l15;
            int aoff = (arow * (2 * KT) + ko2) ^ ((arow & 7) << 4);
            av[rf] = *(const short8*)(xsb + aoff);
        }
#pragma unroll
        for (int cf = 0; cf < 4; cf++) {
            int brow = w * 64 + cf * 16 + l15;
            int boff = (brow * (2 * KT) + ko2) ^ ((brow & 7) << 4);
            bv[cf] = *(const short8*)(wsb + boff);
        }
#pragma unroll
        for (int rf = 0; rf < 4; rf++)
#pragma unroll
            for (int cf = 0; cf < 4; cf++)
                acc[rf][cf] = __builtin_amdgcn_mfma_f32_16x16x32_bf16(av[rf], bv[cf],
                                                                      acc[rf][cf], 0, 0, 0);
    }
    // ---- store D -> hout (bf16)
#pragma unroll
    for (int rf = 0; rf < 4; rf++) {
#pragma unroll
        for (int cf = 0; cf < 4; cf++) {
            int chan = cb0 + w * 64 + cf * 16 + l15;
#pragma unroll
            for (int j = 0; j < 4; j++) {
                int node = row0 + rf * 16 + kg * 4 + j;
                if (node < N)
                    hout[(size_t)node * HC + chan] = (ushort)bf16bits(acc[rf][cf][j]);
            }
        }
    }
    // ---- asv/adv epilogue (only on col-block 0 to avoid duplicate writes)
    if (cb0 == 0) {
        int h = t & 7;
        for (int rr = t >> 3; rr < 64; rr += 32) {
            int node = row0 + rr;
            if (node >= N) continue;
            float su = 0.f, sv = 0.f;
            for (int kb = 0; kb < Kin / 8; kb++) {
                int off = (rr * (2 * KT) + kb * 16) ^ ((rr & 7) << 4);
                short8 xv = *(const short8*)(xsb + off);
#pragma unroll
                for (int j = 0; j < 8; j++) {
                    float f = bf2f_us((unsigned short)xv[j]);
                    su += f * u[(kb * 8 + j) * 8 + h];
                    sv += f * v[(kb * 8 + j) * 8 + h];
                }
            }
            asv[(size_t)node * 8 + h] = su;
            adv[(size_t)node * 8 + h] = sv;
        }
    }
}

// ---------------------------------------------------------------------------
// Fused softmax+aggregation v3 (software-pipelined): one WAVE per dst node.
// The gather wall is latency x concurrency (hbuf fits L3; 247 MB FETCH at
// 3.5 TB/s matches ~2 MB in flight / ~650ns L3 latency, not a BW ceiling).
// Depth-2 pipeline: prefetch next quad's src indices + asv logits while the
// current quad's hbuf loads + FMA stream run -> ~2x outstanding requests.
// Traffic axes bracketed earlier: head-split (r2) -60% FETCH but 8x VALU ->
// worse; fp8 messages (r4) fail accuracy. Math identical to round-1 agg.
__global__ void agg_kernel(const int* __restrict__ rp, const int* __restrict__ src_csr,
                           const float* __restrict__ asv, const float* __restrict__ adv,
                           const ushort* __restrict__ hbuf, const float* __restrict__ bias,
                           float* __restrict__ xout, int N, int dorelu) {
    int gw = (blockIdx.x * blockDim.x + threadIdx.x) >> 6;  // node id
    int lane = threadIdx.x & 63;
    if (gw >= N) return;
    int head = lane >> 3;
    size_t lofs = 8 * (size_t)lane;
    int jb = rp[gw], je = rp[gw + 1];
    float ad = adv[(size_t)gw * 8 + head];
    float acc[8];
#pragma unroll
    for (int r = 0; r < 8; r++) acc[r] = 0.f;
    float den = 0.f;
    int j = jb;
    // pipeline registers: src indices + asv logits for the CURRENT quad
    int s0 = 0, s1 = 0, s2 = 0, s3 = 0;
    float a0 = 0.f, a1 = 0.f, a2 = 0.f, a3 = 0.f;
    if (j + 4 <= je) {
        s0 = src_csr[j];     s1 = src_csr[j + 1];
        s2 = src_csr[j + 2]; s3 = src_csr[j + 3];
        a0 = asv[(size_t)s0 * 8 + head];
        a1 = asv[(size_t)s1 * 8 + head];
        a2 = asv[(size_t)s2 * 8 + head];
        a3 = asv[(size_t)s3 * 8 + head];
    }
    while (j + 4 <= je) {
        // issue current quad's hbuf loads immediately (addresses ready)
        uint4 p0 = *(const uint4*)(hbuf + (size_t)s0 * HC + lofs);
        uint4 p1 = *(const uint4*)(hbuf + (size_t)s1 * HC + lofs);
        uint4 p2 = *(const uint4*)(hbuf + (size_t)s2 * HC + lofs);
        uint4 p3 = *(const uint4*)(hbuf + (size_t)s3 * HC + lofs);
        int jn = j + 4;
        bool more = (jn + 4 <= je);
        int t0 = s0, t1 = s1, t2 = s2, t3 = s3;
        float b0 = a0, b1 = a1, b2 = a2, b3 = a3;
        if (more) {
            // prefetch NEXT quad's src + asv; latency hides under this
            // quad's unpack/FMA stream below
            t0 = src_csr[jn];     t1 = src_csr[jn + 1];
            t2 = src_csr[jn + 2]; t3 = src_csr[jn + 3];
            b0 = asv[(size_t)t0 * 8 + head];
            b1 = asv[(size_t)t1 * 8 + head];
            b2 = asv[(size_t)t2 * 8 + head];
            b3 = asv[(size_t)t3 * 8 + head];
        }
        float w0 = __expf(lrelu(a0 + ad));
        float w1 = __expf(lrelu(a1 + ad));
        float w2 = __expf(lrelu(a2 + ad));
        float w3 = __expf(lrelu(a3 + ad));
        den += (w0 + w1) + (w2 + w3);
        acc[0] += w0 * bf2f_lo(p0.x); acc[1] += w0 * bf2f_hi(p0.x);
        acc[2] += w0 * bf2f_lo(p0.y); acc[3] += w0 * bf2f_hi(p0.y);
        acc[4] += w0 * bf2f_lo(p0.z); acc[5] += w0 * bf2f_hi(p0.z);
        acc[6] += w0 * bf2f_lo(p0.w); acc[7] += w0 * bf2f_hi(p0.w);
        acc[0] += w1 * bf2f_lo(p1.x); acc[1] += w1 * bf2f_hi(p1.x);
        acc[2] += w1 * bf2f_lo(p1.y); acc[3] += w1 * bf2f_hi(p1.y);
        acc[4] += w1 * bf2f_lo(p1.z); acc[5] += w1 * bf2f_hi(p1.z);
        acc[6] += w1 * bf2f_lo(p1.w); acc[7] += w1 * bf2f_hi(p1.w);
        acc[0] += w2 * bf2f_lo(p2.x); acc[1] += w2 * bf2f_hi(p2.x);
        acc[2] += w2 * bf2f_lo(p2.y); acc[3] += w2 * bf2f_hi(p2.y);
        acc[4] += w2 * bf2f_lo(p2.z); acc[5] += w2 * bf2f_hi(p2.z);
        acc[6] += w2 * bf2f_lo(p2.w); acc[7] += w2 * bf2f_hi(p2.w);
        acc[0] += w3 * bf2f_lo(p3.x); acc[1] += w3 * bf2f_hi(p3.x);
        acc[2] += w3 * bf2f_lo(p3.y); acc[3] += w3 * bf2f_hi(p3.y);
        acc[4] += w3 * bf2f_lo(p3.z); acc[5] += w3 * bf2f_hi(p3.z);
        acc[6] += w3 * bf2f_lo(p3.w); acc[7] += w3 * bf2f_hi(p3.w);
        s0 = t0; s1 = t1; s2 = t2; s3 = t3;
        a0 = b0; a1 = b1; a2 = b2; a3 = b3;
        j = jn;
    }
    for (; j < je; j++) {
        int sc = src_csr[j];
        float w0 = __expf(lrelu(asv[(size_t)sc * 8 + head] + ad));
        uint4 p0 = *(const uint4*)(hbuf + (size_t)sc * HC + lofs);
        den += w0;
        acc[0] += w0 * bf2f_lo(p0.x); acc[1] += w0 * bf2f_hi(p0.x);
        acc[2] += w0 * bf2f_lo(p0.y); acc[3] += w0 * bf2f_hi(p0.y);
        acc[4] += w0 * bf2f_lo(p0.z); acc[5] += w0 * bf2f_hi(p0.z);
        acc[6] += w0 * bf2f_lo(p0.w); acc[7] += w0 * bf2f_hi(p0.w);
    }
    float inv = 1.f / (den + 1e-16f);
#pragma unroll
    for (int r = 0; r < 8; r++) {
        acc[r] *= inv;
        acc[r] += __shfl_xor(acc[r], 8);
        acc[r] += __shfl_xor(acc[r], 16);
        acc[r] += __shfl_xor(acc[r], 32);
    }
    if (lane < 8) {
        const float4* b4 = (const float4*)(bias + 8 * lane);
        float4 bv0 = b4[0], bv1 = b4[1];
        float4 o0, o1;
        o0.x = acc[0] * 0.125f + bv0.x;
        o0.y = acc[1] * 0.125f + bv0.y;
        o0.z = acc[2] * 0.125f + bv0.z;
        o0.w = acc[3] * 0.125f + bv0.w;
        o1.x = acc[4] * 0.125f + bv1.x;
        o1.y = acc[5] * 0.125f + bv1.y;
        o1.z = acc[6] * 0.125f + bv1.z;
        o1.w = acc[7] * 0.125f + bv1.w;
        if (dorelu) {
            o0.x = fmaxf(o0.x, 0.f); o0.y = fmaxf(o0.y, 0.f);
            o0.z = fmaxf(o0.z, 0.f); o0.w = fmaxf(o0.w, 0.f);
            o1.x = fmaxf(o1.x, 0.f); o1.y = fmaxf(o1.y, 0.f);
            o1.z = fmaxf(o1.z, 0.f); o1.w = fmaxf(o1.w, 0.f);
        }
        float4* op = (float4*)(xout + (size_t)gw * CH + 8 * lane);
        op[0] = o0;
        op[1] = o1;
    }
}

// ---------------------------------------------------------------------------
// Fused mean-pool + linear: one block per graph (batch sorted, binary search).
__global__ void poolfinal_kernel(const float* __restrict__ x, const int* __restrict__ batch,
                                 const float* __restrict__ linW, const float* __restrict__ linb,
                                 float* __restrict__ out, int N) {
    int g = blockIdx.x;
    int lo = 0, hi = N;
    while (lo < hi) { int m = (lo + hi) >> 1; if (batch[m] < g) lo = m + 1; else hi = m; }
    int lo2 = lo, hi2 = N;
    while (lo2 < hi2) { int m = (lo2 + hi2) >> 1; if (batch[m] < g + 1) lo2 = m + 1; else hi2 = m; }
    int n0 = lo, n1 = lo2;
    int c  = threadIdx.x & 63;
    int nl = threadIdx.x >> 6;
    float acc = 0.f;
    for (int n = n0 + nl; n < n1; n += 4)
        acc += x[(size_t)n * CH + c];
    __shared__ float lds[4][64];
    lds[nl][c] = acc;
    __syncthreads();
    __shared__ float pooled[64];
    if (threadIdx.x < 64) {
        float cnt = (float)max(n1 - n0, 1);
        pooled[threadIdx.x] = (lds[0][threadIdx.x] + lds[1][threadIdx.x] +
                               lds[2][threadIdx.x] + lds[3][threadIdx.x]) / cnt;
    }
    __syncthreads();
    if (threadIdx.x < 2) {
        int k = threadIdx.x;
        float s = 0.f;
#pragma unroll
        for (int cc = 0; cc < CH; cc++) s += pooled[cc] * linW[cc * 2 + k];
        out[g * 2 + k] = s + linb[k];
    }
}

// ---------------------------------------------------------------------------
extern "C" void kernel_launch(void* const* d_in, const int* in_sizes, int n_in,
                              void* d_out, int out_size, void* d_ws, size_t ws_size,
                              hipStream_t stream) {
    const float* x      = (const float*)d_in[0];
    const int*   ei     = (const int*)d_in[1];
    const int*   batch  = (const int*)d_in[3];
    const float* gamma  = (const float*)d_in[4];
    const float* beta   = (const float*)d_in[5];
    const float* W1     = (const float*)d_in[6];
    const float* a1s    = (const float*)d_in[7];
    const float* a1d    = (const float*)d_in[8];
    const float* b1     = (const float*)d_in[9];
    const float* W2     = (const float*)d_in[10];
    const float* a2s    = (const float*)d_in[11];
    const float* a2d    = (const float*)d_in[12];
    const float* b2     = (const float*)d_in[13];
    const float* W3     = (const float*)d_in[14];
    const float* a3s    = (const float*)d_in[15];
    const float* a3d    = (const float*)d_in[16];
    const float* b3     = (const float*)d_in[17];
    const float* linW   = (const float*)d_in[18];
    const float* linb   = (const float*)d_in[19];
    float* out = (float*)d_out;

    const int N  = in_sizes[0] / 16;
    const int E  = in_sizes[1] / 2;
    const int E2 = E + N;

    // Workspace layout (256B aligned slices)
    char* p = (char*)d_ws;
    size_t off = 0;
    auto alloc = [&](size_t bytes) {
        void* r = p + off;
        off += (bytes + 255) & ~(size_t)255;
        return r;
    };
    ushort* hbuf     = (ushort*)alloc((size_t)N * HC * 2);   // bf16 h
    float* xa        = (float*)alloc((size_t)N * CH * 4);
    float* xb        = (float*)alloc((size_t)N * CH * 4);
    float* asv       = (float*)alloc((size_t)N * HEADS * 4);
    float* adv       = (float*)alloc((size_t)N * HEADS * 4);
    float* stats     = (float*)alloc(64 * 4);
    float* partials  = (float*)alloc((size_t)BNB * 32 * 4);
    float* uv        = (float*)alloc(2304 * 4);
    int*   rowptr    = (int*)alloc((size_t)(N + 1) * 4);
    int*   cursor    = (int*)alloc((size_t)N * 4);
    int*   counts    = (int*)alloc((size_t)N * 4);
    int*   src_csr   = (int*)alloc((size_t)E2 * 4);
    ushort* wt1      = (ushort*)alloc(512 * 32 * 2);  // Wt bf16, layer1 K-pad 32
    ushort* wt2      = (ushort*)alloc(512 * 64 * 2);
    ushort* wt3      = (ushort*)alloc(512 * 64 * 2);
    (void)ws_size;

    const int TB = 256;
    int gE2 = (E2 + TB - 1) / TB;
    int gWv = (N * 64 + TB - 1) / TB;      // one wave per node
    int bnChunk = (N + BNB - 1) / BNB;
    int gb = ((N + 63) / 64) * 2;          // MFMA gemm: 64-row x 256-col tiles (1D)

    // zero-init count accumulators
    hipMemsetAsync(counts, 0, (size_t)N * 4, stream);

    // D1: BN stats partials || CSR count || Wt bf16 prep (independent, merged)
    stats_count_kernel<<<BNB + gE2 + WPB, TB, 0, stream>>>(x, partials, N, bnChunk,
                                                           ei, E, E2, counts,
                                                           W1, W2, W3, wt1, wt2, wt3);
    // D2: uv precompute + BN finalize + CSR scan (merged dispatch)
    uv_scan_kernel<<<5, 1024, 0, stream>>>(W1, a1s, a1d, W2, a2s, a2d, W3, a3s, a3d,
                                           uv, partials, stats, gamma, beta, N, BNB,
                                           counts, rowptr, cursor);

    // ---- Layer 1 GEMM || CSR scatter (independent, merged dispatch) ----
    gemm_kernel<32, true><<<gb + gE2, TB, 0, stream>>>(x, wt1, hbuf, N, 16,
                                                       stats + 32, stats + 48,
                                                       uv + 0, uv + 128, asv, adv,
                                                       ei, E, E2, cursor, src_csr, gb);
    agg_kernel<<<gWv, TB, 0, stream>>>(rowptr, src_csr, asv, adv, hbuf, b1, xa, N, 1);

    // ---- Layer 2 ----
    gemm_kernel<64, false><<<gb, TB, 0, stream>>>(xa, wt2, hbuf, N, 64, nullptr, nullptr,
                                                  uv + 256, uv + 768, asv, adv,
                                                  nullptr, 0, 0, nullptr, nullptr, gb);
    agg_kernel<<<gWv, TB, 0, stream>>>(rowptr, src_csr, asv, adv, hbuf, b2, xb, N, 1);

    // ---- Layer 3 ----
    gemm_kernel<64, false><<<gb, TB, 0, stream>>>(xb, wt3, hbuf, N, 64, nullptr, nullptr,
                                                  uv + 1280, uv + 1792, asv, adv,
                                                  nullptr, 0, 0, nullptr, nullptr, gb);
    agg_kernel<<<gWv, TB, 0, stream>>>(rowptr, src_csr, asv, adv, hbuf, b3, xa, N, 0);

    // ---- Fused mean-pool + linear ----
    poolfinal_kernel<<<NGR, TB, 0, stream>>>(xa, batch, linW, linb, out, N);
}